// Round 9
// baseline (122.247 us; speedup 1.0000x reference)
//
#include <hip/hip_runtime.h>
#include <hip/hip_bf16.h>

// GNN2: 3-layer GAT over 16384 independent 32-node cliques.
// TWO waves per graph (2 graphs / 256-thread block): wave A = N-tiles 0-3 /
// heads 0,1 / feature-cols 0-63; wave B = N-tiles 4-8 (incl. score) / heads
// 2,3 / cols 64-127. Halves LDS per wave -> 8 blocks/CU (32 waves).
// mfma_f32_16x16x32_bf16 GEMMs + aggregation; scores fused into the GEMM via
// pre-multiplied Wa = W @ [a_src|a_dst] cols pre-scaled by log2(e) (exp2-domain
// softmax, no max-subtraction). f32 accumulate. __syncthreads at phase edges.

typedef __attribute__((ext_vector_type(8))) short short8;
typedef __attribute__((ext_vector_type(4))) short short4v;
typedef __attribute__((ext_vector_type(4))) float f32x4;

#define MFMA16(a,b,c) __builtin_amdgcn_mfma_f32_16x16x32_bf16(a,b,c,0,0,0)
#define L2E 1.4426950408889634f

__device__ __forceinline__ short f2bf(float f) {
    __hip_bfloat16 h = __float2bfloat16(f);
    return *reinterpret_cast<short*>(&h);
}
__device__ __forceinline__ float fexp2(float x) { return __builtin_amdgcn_exp2f(x); }

// ---------------- pre-kernel: tiled transposed bf16 weights in ws ----------------
//  wt1 [0,4608):       NT=9, KC=1. n<128 -> W1[k][n] (k<16 else 0); 128..135 -> L2E*Wa1
//  wt2 [4608,23040):   NT=9, KC=4. same for W2/Wa2
//  wt3 [23040,27136):  NT=2, KC=4. n<24 -> W3[k][n] (packed hd*6+dl); 24..31 -> L2E*Wa3
__global__ __launch_bounds__(256) void build_wt(
    const float* __restrict__ W1, const float* __restrict__ as1, const float* __restrict__ ad1,
    const float* __restrict__ W2, const float* __restrict__ as2, const float* __restrict__ ad2,
    const float* __restrict__ W3, const float* __restrict__ as3, const float* __restrict__ ad3,
    short* __restrict__ ws)
{
    int i = blockIdx.x * 256 + threadIdx.x;
    float val = 0.f;
    if (i < 4608) {
        int n = i >> 5, k = i & 31;
        if (k < 16) {
            if (n < 128) val = W1[k*128 + n];
            else if (n < 136) {
                int cc = n - 128; const float* a = (cc < 4) ? as1 : ad1;
                for (int dl = 0; dl < 32; ++dl)
                    val += W1[k*128 + (cc&3)*32 + dl] * a[(cc&3)*32 + dl];
                val *= L2E;
            }
        }
        ws[i] = f2bf(val);
    } else if (i < 23040) {
        int j = i - 4608;
        int kq = j & 31, c = (j >> 5) & 15, kc = (j >> 9) & 3, nt = j >> 11;
        int n = nt*16 + c, k = kc*32 + kq;
        if (n < 128) val = W2[k*128 + n];
        else if (n < 136) {
            int cc = n - 128; const float* a = (cc < 4) ? as2 : ad2;
            for (int dl = 0; dl < 32; ++dl)
                val += W2[k*128 + (cc&3)*32 + dl] * a[(cc&3)*32 + dl];
            val *= L2E;
        }
        ws[i] = f2bf(val);
    } else {
        int j = i - 23040;
        int kq = j & 31, c = (j >> 5) & 15, kc = (j >> 9) & 3, nt = j >> 11;
        int n = nt*16 + c, k = kc*32 + kq;
        if (n < 24) val = W3[k*24 + n];
        else {
            int cc = n - 24; const float* a = (cc < 4) ? as3 : ad3;
            for (int dl = 0; dl < 6; ++dl)
                val += W3[k*24 + (cc&3)*6 + dl] * a[(cc&3)*6 + dl];
            val *= L2E;
        }
        ws[i] = f2bf(val);
    }
}

// ---------------- main-kernel phases ----------------
// A-frag: row=lane&15, k=8*(lane>>4)+v; B-frag: col=lane&15, same k;
// D: col=lane&15, row=4*(lane>>4)+r. [m89/m93]
// xb: [32][136] bf16 (stride-136 pad). ht: [128][32] bf16 overlaid on xb,
// 4-short granule gl of row d at gl ^ ((d&15)>>1). ss: f32[8][32] separate.

template<int KC>
__device__ __forceinline__ void preload_a(const short* xb, int c, int q, short8 (&afr)[2][KC])
{
    #pragma unroll
    for (int mt = 0; mt < 2; ++mt)
      #pragma unroll
      for (int kc = 0; kc < KC; ++kc)
        afr[mt][kc] = *(const short8*)&xb[(mt*16 + c)*136 + kc*32 + q*8];
}

// This wave's GEMM tiles: A(wl=0): nt 0-3; B(wl=1): nt 4-7 + score tile (nt 8).
template<int KC>
__device__ __forceinline__ void gemm_ht(const short8 (&afr)[2][KC], const short* __restrict__ wt,
                                        short* buf, float* ss, int c, int q, int wl)
{
    const f32x4 zf = {0.f, 0.f, 0.f, 0.f};
    int sw = c >> 1;
    #pragma unroll
    for (int ntl = 0; ntl < 4; ++ntl) {
        int nt = wl*4 + ntl;
        f32x4 a0 = zf, a1 = zf;
        #pragma unroll
        for (int kc = 0; kc < KC; ++kc) {
            short8 bfr = *(const short8*)&wt[((nt*KC + kc)*16 + c)*32 + q*8];
            a0 = MFMA16(afr[0][kc], bfr, a0);
            a1 = MFMA16(afr[1][kc], bfr, a1);
        }
        int d = nt*16 + c;
        short4v h0, h1;
        #pragma unroll
        for (int r = 0; r < 4; ++r) { h0[r] = f2bf(a0[r]); h1[r] = f2bf(a1[r]); }
        *(short4v*)&buf[d*32 + ((q ^ sw))*4]     = h0;
        *(short4v*)&buf[d*32 + (((4+q) ^ sw))*4] = h1;
    }
    if (wl == 1) {                       // score tile
        f32x4 a0 = zf, a1 = zf;
        #pragma unroll
        for (int kc = 0; kc < KC; ++kc) {
            short8 bfr = *(const short8*)&wt[((8*KC + kc)*16 + c)*32 + q*8];
            a0 = MFMA16(afr[0][kc], bfr, a0);
            a1 = MFMA16(afr[1][kc], bfr, a1);
        }
        if (c < 8) {      // rows c<4 = s_src head c, c>=4 = s_dst head c-4
            *(f32x4*)&ss[c*32 + q*4]      = a0;
            *(f32x4*)&ss[c*32 + 16 + q*4] = a1;
        }
    }
}

// This wave's heads (hd = wl*2+hh): P-frags (exp2 domain), agg MFMAs, finish
// (normalize + bias) straight into pend registers.
__device__ __forceinline__ void agg_pend(const short* buf, const float* ss,
                                         const float* bias, int c, int q, int wl,
                                         short4v (&pend)[4][2])
{
    const f32x4 zf = {0.f, 0.f, 0.f, 0.f};
    int sw = c >> 1;
    #pragma unroll
    for (int hh = 0; hh < 2; ++hh) {
        int hd = wl*2 + hh;
        f32x4 v0 = *(const f32x4*)&ss[hd*32 + q*8];
        f32x4 v1 = *(const f32x4*)&ss[hd*32 + q*8 + 4];
        short8 pf[2]; float rdh[2];
        #pragma unroll
        for (int it = 0; it < 2; ++it) {
            float sd = ss[(4+hd)*32 + it*16 + c];
            float den = 0.f; short8 t;
            #pragma unroll
            for (int v = 0; v < 8; ++v) {
                float sj = (v < 4) ? v0[v] : v1[v-4];
                float e = sd + sj; e = fmaxf(e, 0.2f*e);   // lrelu, log2 domain
                float p = fexp2(e);
                den += p;
                t[v] = f2bf(p);
            }
            den += __shfl_xor(den, 16, 64);
            den += __shfl_xor(den, 32, 64);
            pf[it] = t; rdh[it] = 1.0f / den;
        }
        #pragma unroll
        for (int m2 = 0; m2 < 2; ++m2) {
            int mtl = hh*2 + m2, mt = wl*4 + mtl, d = mt*16 + c;
            short4v lo = *(const short4v*)&buf[d*32 + ((2*q)   ^ sw)*4];
            short4v hi = *(const short4v*)&buf[d*32 + ((2*q+1) ^ sw)*4];
            short8 af = __builtin_shufflevector(lo, hi, 0,1,2,3,4,5,6,7);
            f32x4 bv = *(const f32x4*)&bias[mt*16 + q*4];
            #pragma unroll
            for (int it = 0; it < 2; ++it) {
                f32x4 acc = MFMA16(af, pf[it], zf);
                short4v o;
                #pragma unroll
                for (int r = 0; r < 4; ++r) o[r] = f2bf(fmaf(acc[r], rdh[it], bv[r]));
                pend[mtl][it] = o;
            }
        }
    }
}

__device__ __forceinline__ void write_xb(const short4v (&pend)[4][2], short* xb,
                                         int c, int q, int wl)
{
    #pragma unroll
    for (int mtl = 0; mtl < 4; ++mtl) {
        int mt = wl*4 + mtl;
        #pragma unroll
        for (int it = 0; it < 2; ++it) {
            int ii = it*16 + c;
            *(short4v*)&xb[ii*136 + mt*16 + q*4] = pend[mtl][it];
        }
    }
}

template<int KC>
__device__ __forceinline__ void layer12(short* buf, float* ss, const short* __restrict__ wt,
                                        const float* bias, int c, int q, int wl)
{
    short8 afr[2][KC];
    preload_a<KC>(buf, c, q, afr);
    __syncthreads();                       // preloads done; buf reusable as ht
    gemm_ht<KC>(afr, wt, buf, ss, c, q, wl);
    __syncthreads();                       // ht + ss ready
    short4v pend[4][2];
    agg_pend(buf, ss, bias, c, q, wl, pend);
    __syncthreads();                       // all ht/ss reads done
    write_xb(pend, buf, c, q, wl);
}

// Layer 3: packed 24+8 GEMM (wave wl does tile nt=wl), head-padded ht rows,
// P-as-A aggregation, in-register node-mean -> mcol[24] (in ss[0..23]).
__device__ __forceinline__ void layer3(short* buf, float* ss, const short* __restrict__ wt,
                                       const float* b3, int c, int q, int lane, int wl)
{
    const f32x4 zf = {0.f, 0.f, 0.f, 0.f};
    short8 afr[2][4];
    preload_a<4>(buf, c, q, afr);
    __syncthreads();
    {   // zero-fill pad rows hd*16+dl, dl 6..15 (320 b64 slots over 128 lanes)
        const short4v z4 = {0, 0, 0, 0};
        #pragma unroll
        for (int k = 0; k < 3; ++k) {
            int flat = (wl*64 + lane) + k*128;
            if (flat < 320) {
                int z = flat >> 3, gg = flat & 7;
                int row = (z/10)*16 + 6 + (z%10);
                *(short4v*)&buf[row*32 + gg*4] = z4;
            }
        }
    }
    {   // GEMM tile nt = wl
        int nt = wl;
        f32x4 a0 = zf, a1 = zf;
        #pragma unroll
        for (int kc = 0; kc < 4; ++kc) {
            short8 bfr = *(const short8*)&wt[((nt*4 + kc)*16 + c)*32 + q*8];
            a0 = MFMA16(afr[0][kc], bfr, a0);
            a1 = MFMA16(afr[1][kc], bfr, a1);
        }
        int p = nt*16 + c;
        if (p < 24) {
            int row = (p/6)*16 + (p%6);
            int sw3 = (row & 15) >> 1;
            short4v h0, h1;
            #pragma unroll
            for (int r = 0; r < 4; ++r) { h0[r] = f2bf(a0[r]); h1[r] = f2bf(a1[r]); }
            *(short4v*)&buf[row*32 + ((q ^ sw3))*4]     = h0;
            *(short4v*)&buf[row*32 + (((4+q) ^ sw3))*4] = h1;
        } else if (c >= 8) {   // score cols (only wl==1 reaches here)
            *(f32x4*)&ss[(c-8)*32 + q*4]      = a0;
            *(f32x4*)&ss[(c-8)*32 + 16 + q*4] = a1;
        }
    }
    __syncthreads();                       // ht + ss + zero-pad ready
    int sw = c >> 1;
    float vout[2];
    #pragma unroll
    for (int hh = 0; hh < 2; ++hh) {
        int hd = wl*2 + hh;
        f32x4 v0 = *(const f32x4*)&ss[hd*32 + q*8];
        f32x4 v1 = *(const f32x4*)&ss[hd*32 + q*8 + 4];
        short8 pf[2];
        #pragma unroll
        for (int it = 0; it < 2; ++it) {
            float sd = ss[(4+hd)*32 + it*16 + c];
            float pv[8]; float den = 0.f;
            #pragma unroll
            for (int v = 0; v < 8; ++v) {
                float sj = (v < 4) ? v0[v] : v1[v-4];
                float e = sd + sj; e = fmaxf(e, 0.2f*e);
                pv[v] = fexp2(e);
                den += pv[v];
            }
            den += __shfl_xor(den, 16, 64);
            den += __shfl_xor(den, 32, 64);
            float rd = 1.0f / den;
            short8 t;
            #pragma unroll
            for (int v = 0; v < 8; ++v) t[v] = f2bf(pv[v] * rd);
            pf[it] = t;
        }
        int rl = hd*16 + c;
        short4v lo = *(const short4v*)&buf[rl*32 + ((2*q)   ^ sw)*4];
        short4v hi = *(const short4v*)&buf[rl*32 + ((2*q+1) ^ sw)*4];
        short8 bf_ = __builtin_shufflevector(lo, hi, 0,1,2,3,4,5,6,7);
        f32x4 o0 = MFMA16(pf[0], bf_, zf);   // D: row=i(4q+r), col=dl(c) in head hd
        f32x4 o1 = MFMA16(pf[1], bf_, zf);
        float s = (o0[0]+o0[1]) + (o0[2]+o0[3]) + (o1[0]+o1[1]) + (o1[2]+o1[3]);
        s += __shfl_xor(s, 16, 64);
        s += __shfl_xor(s, 32, 64);
        vout[hh] = s;
    }
    __syncthreads();                       // ss score reads done
    if (q == 0 && c < 6) {
        #pragma unroll
        for (int hh = 0; hh < 2; ++hh)
            ss[(wl*2 + hh)*6 + c] = vout[hh] * (1.f/32.f) + b3[(wl*2 + hh)*6 + c];
    }
    __syncthreads();                       // mcol ready
}

__global__ __launch_bounds__(256, 8) void gat_mfma(
    const float* __restrict__ xs, const float* __restrict__ pe,
    const short* __restrict__ ws,
    const float* __restrict__ b1, const float* __restrict__ b2, const float* __restrict__ b3,
    const float* __restrict__ LW, const float* __restrict__ lb,
    float* __restrict__ out, int R)
{
    __shared__ short buf[2][4352];      // per-graph union: xb[32][136] <-> ht[128][32]
    __shared__ float ssx[2][256];       // per-graph scores [8][32]; mcol in [0..23]

    int t = threadIdx.x;
    int w = t >> 6, lane = t & 63;
    int gl = w >> 1, wl = w & 1;
    int c = lane & 15, q = lane >> 4;
    int g = blockIdx.x * 2 + gl;
    int b = g / R;

    short* xb = buf[gl];
    float* ss = ssx[gl];

    // ---- build x0 [32][16] bf16 (cols 16..31 zero) — wave A only ----
    if (wl == 0) {
        int j = lane >> 1, half = lane & 1;
        float v[8];
        if (half == 0) {
            v[0] = xs[g*32 + j];
            #pragma unroll
            for (int kk = 0; kk < 7; ++kk) v[1+kk] = pe[b*480 + j*15 + kk];
        } else {
            #pragma unroll
            for (int kk = 0; kk < 8; ++kk) v[kk] = pe[b*480 + j*15 + 7 + kk];
        }
        short8 px;
        #pragma unroll
        for (int kk = 0; kk < 8; ++kk) px[kk] = f2bf(v[kk]);
        *(short8*)&xb[j*136 + half*8] = px;
        *(short8*)&xb[j*136 + 16 + half*8] = (short8){0,0,0,0,0,0,0,0};
    }
    __syncthreads();

    const short* wt1 = ws;
    const short* wt2 = ws + 4608;
    const short* wt3 = ws + 23040;

    layer12<1>(xb, ss, wt1, b1, c, q, wl);
    __syncthreads();
    layer12<4>(xb, ss, wt2, b2, c, q, wl);
    __syncthreads();
    layer3(xb, ss, wt3, b3, c, q, lane, wl);

    // ---- epilogue: out[g] = mcol @ lin_w + lin_b (f32) — wave A only ----
    if (wl == 0) {
        float o = lb[lane];
        #pragma unroll
        for (int cc = 0; cc < 24; ++cc)
            o = fmaf(ss[cc], LW[cc*64 + lane], o);
        out[g*64 + lane] = o;
    }
}

extern "C" void kernel_launch(void* const* d_in, const int* in_sizes, int n_in,
                              void* d_out, int out_size, void* d_ws, size_t ws_size,
                              hipStream_t stream) {
    const float* xs  = (const float*)d_in[0];
    const float* pe  = (const float*)d_in[1];
    const float* W1  = (const float*)d_in[2];
    const float* as1 = (const float*)d_in[3];
    const float* ad1 = (const float*)d_in[4];
    const float* b1  = (const float*)d_in[5];
    const float* W2  = (const float*)d_in[6];
    const float* as2 = (const float*)d_in[7];
    const float* ad2 = (const float*)d_in[8];
    const float* b2  = (const float*)d_in[9];
    const float* W3  = (const float*)d_in[10];
    const float* as3 = (const float*)d_in[11];
    const float* ad3 = (const float*)d_in[12];
    const float* b3  = (const float*)d_in[13];
    const float* LW  = (const float*)d_in[14];
    const float* lb  = (const float*)d_in[15];
    float* o = (float*)d_out;
    short* ws = (short*)d_ws;

    int G = in_sizes[0] / 32;       // B*R graphs (16384)
    int B = in_sizes[1] / 480;      // pos_enc = B*32*15
    int R = G / B;

    build_wt<<<dim3(106), dim3(256), 0, stream>>>(W1, as1, ad1, W2, as2, ad2,
                                                  W3, as3, ad3, ws);
    gat_mfma<<<dim3(G/2), dim3(256), 0, stream>>>(xs, pe, ws, b1, b2, b3, LW, lb, o, R);
}

// Round 10
// 95.051 us; speedup vs baseline: 1.2861x; 1.2861x over previous
//
#include <hip/hip_runtime.h>
#include <hip/hip_bf16.h>

// GNN2: 3-layer GAT over 16384 independent 32-node cliques.
// One WAVE per graph (4 graphs / 256-thread block), zero barriers.
// mfma_f32_16x16x32_bf16 for GEMMs + aggregation; scores fused into the GEMM
// via pre-multiplied Wa = W @ [a_src|a_dst] columns pre-scaled by log2(e)
// (exp2-domain softmax, no max-subtraction). f32 accumulate.
// Round-7 structure (96.4us, 4 blk/CU) + v_rcp_f32 for 1/den + s_setprio(1)
// around MFMA clusters (independent waves -> attn-like regime, T5/m191).

typedef __attribute__((ext_vector_type(8))) short short8;
typedef __attribute__((ext_vector_type(4))) short short4v;
typedef __attribute__((ext_vector_type(4))) float f32x4;

#define MFMA16(a,b,c) __builtin_amdgcn_mfma_f32_16x16x32_bf16(a,b,c,0,0,0)
#define L2E 1.4426950408889634f

__device__ __forceinline__ short f2bf(float f) {
    __hip_bfloat16 h = __float2bfloat16(f);
    return *reinterpret_cast<short*>(&h);
}
__device__ __forceinline__ float fexp2(float x) { return __builtin_amdgcn_exp2f(x); }
__device__ __forceinline__ float frcp(float x) {
    float r;
    asm volatile("v_rcp_f32 %0, %1" : "=v"(r) : "v"(x));
    return r;
}

// ---------------- pre-kernel: tiled transposed bf16 weights in ws ----------------
//  wt1 [0,4608):       NT=9, KC=1. n<128 -> W1[k][n] (k<16 else 0); 128..135 -> L2E*Wa1
//  wt2 [4608,23040):   NT=9, KC=4. same for W2/Wa2
//  wt3 [23040,27136):  NT=2, KC=4. n<24 -> W3[k][n] (packed hd*6+dl); 24..31 -> L2E*Wa3
__global__ __launch_bounds__(256) void build_wt(
    const float* __restrict__ W1, const float* __restrict__ as1, const float* __restrict__ ad1,
    const float* __restrict__ W2, const float* __restrict__ as2, const float* __restrict__ ad2,
    const float* __restrict__ W3, const float* __restrict__ as3, const float* __restrict__ ad3,
    short* __restrict__ ws)
{
    int i = blockIdx.x * 256 + threadIdx.x;
    float val = 0.f;
    if (i < 4608) {                       // layer 1 (KC=1 -> [n][k])
        int n = i >> 5, k = i & 31;
        if (k < 16) {
            if (n < 128) val = W1[k*128 + n];
            else if (n < 136) {
                int cc = n - 128; const float* a = (cc < 4) ? as1 : ad1;
                for (int dl = 0; dl < 32; ++dl)
                    val += W1[k*128 + (cc&3)*32 + dl] * a[(cc&3)*32 + dl];
                val *= L2E;
            }
        }
        ws[i] = f2bf(val);
    } else if (i < 23040) {               // layer 2
        int j = i - 4608;
        int kq = j & 31, c = (j >> 5) & 15, kc = (j >> 9) & 3, nt = j >> 11;
        int n = nt*16 + c, k = kc*32 + kq;
        if (n < 128) val = W2[k*128 + n];
        else if (n < 136) {
            int cc = n - 128; const float* a = (cc < 4) ? as2 : ad2;
            for (int dl = 0; dl < 32; ++dl)
                val += W2[k*128 + (cc&3)*32 + dl] * a[(cc&3)*32 + dl];
            val *= L2E;
        }
        ws[i] = f2bf(val);
    } else {                              // layer 3 (packed 24 + 8 score)
        int j = i - 23040;
        int kq = j & 31, c = (j >> 5) & 15, kc = (j >> 9) & 3, nt = j >> 11;
        int n = nt*16 + c, k = kc*32 + kq;
        if (n < 24) val = W3[k*24 + n];
        else {
            int cc = n - 24; const float* a = (cc < 4) ? as3 : ad3;
            for (int dl = 0; dl < 6; ++dl)
                val += W3[k*24 + (cc&3)*6 + dl] * a[(cc&3)*6 + dl];
            val *= L2E;
        }
        ws[i] = f2bf(val);
    }
}

// ---------------- main-kernel phases ----------------
// Fragment layout (gfx950 16x16x32 bf16): A: row=lane&15, k=8*(lane>>4)+v;
// B: col=lane&15, k=8*(lane>>4)+v; D: col=lane&15, row=4*(lane>>4)+r. [m89/m93]
// xb: [32][136] bf16. ht: [128][32] bf16 overlaid, 4-short granule gl of row d
// stored at gl ^ ((d&15)>>1). ss: f32[8][32] separate.

// GEMM + ht/score write, per-nt interleaved (A-frags preloaded; xb dead after).
template<int KC, int NT, int NTH>
__device__ __forceinline__ void gemm_ht(short* buf, const short* __restrict__ wt,
                                        float* ss, int c, int q)
{
    const f32x4 zf = {0.f, 0.f, 0.f, 0.f};
    short8 afr[2][KC];
    #pragma unroll
    for (int mt = 0; mt < 2; ++mt)
      #pragma unroll
      for (int kc = 0; kc < KC; ++kc)
        afr[mt][kc] = *(const short8*)&buf[(mt*16 + c)*136 + kc*32 + q*8];
    int sw = c >> 1;
    #pragma unroll
    for (int nt = 0; nt < NT; ++nt) {
        short8 bfr[KC];
        #pragma unroll
        for (int kc = 0; kc < KC; ++kc)
            bfr[kc] = *(const short8*)&wt[((nt*KC + kc)*16 + c)*32 + q*8];
        f32x4 a0 = zf, a1 = zf;
        __builtin_amdgcn_s_setprio(1);
        #pragma unroll
        for (int kc = 0; kc < KC; ++kc) {
            a0 = MFMA16(afr[0][kc], bfr[kc], a0);
            a1 = MFMA16(afr[1][kc], bfr[kc], a1);
        }
        __builtin_amdgcn_s_setprio(0);
        if (nt < NTH) {
            int d = nt*16 + c;
            short4v h0, h1;
            #pragma unroll
            for (int r = 0; r < 4; ++r) { h0[r] = f2bf(a0[r]); h1[r] = f2bf(a1[r]); }
            *(short4v*)&buf[d*32 + ((q ^ sw))*4]     = h0;
            *(short4v*)&buf[d*32 + (((4+q) ^ sw))*4] = h1;
        } else if (c < 8) {   // score tile: rows c<4 = s_src head c, c>=4 = s_dst
            *(f32x4*)&ss[c*32 + q*4]      = a0;
            *(f32x4*)&ss[c*32 + 16 + q*4] = a1;
        }
    }
}

// Fused frag+agg (layers 1-2): per head build P-frags (exp2 domain, no max-sub),
// then 2 MFMAs per M-tile.
__device__ __forceinline__ void agg12(const short* buf, const float* ss,
                                      int c, int q, f32x4 (&acc)[8][2], float (&rden)[4][2])
{
    const f32x4 zf = {0.f, 0.f, 0.f, 0.f};
    int sw = c >> 1;
    #pragma unroll
    for (int hd = 0; hd < 4; ++hd) {
        f32x4 v0 = *(const f32x4*)&ss[hd*32 + q*8];
        f32x4 v1 = *(const f32x4*)&ss[hd*32 + q*8 + 4];
        short8 pf[2];
        #pragma unroll
        for (int it = 0; it < 2; ++it) {
            float sd = ss[(4+hd)*32 + it*16 + c];
            float den = 0.f; short8 t;
            #pragma unroll
            for (int v = 0; v < 8; ++v) {
                float sj = (v < 4) ? v0[v] : v1[v-4];
                float e = sd + sj; e = fmaxf(e, 0.2f*e);   // lrelu, log2 domain
                float p = fexp2(e);
                den += p;
                t[v] = f2bf(p);
            }
            den += __shfl_xor(den, 16, 64);
            den += __shfl_xor(den, 32, 64);
            pf[it] = t; rden[hd][it] = frcp(den);
        }
        #pragma unroll
        for (int m2 = 0; m2 < 2; ++m2) {
            int mt = hd*2 + m2, d = mt*16 + c;
            short4v lo = *(const short4v*)&buf[d*32 + ((2*q)   ^ sw)*4];
            short4v hi = *(const short4v*)&buf[d*32 + ((2*q+1) ^ sw)*4];
            short8 af = __builtin_shufflevector(lo, hi, 0,1,2,3,4,5,6,7);
            __builtin_amdgcn_s_setprio(1);
            acc[mt][0] = MFMA16(af, pf[0], zf);
            acc[mt][1] = MFMA16(af, pf[1], zf);
            __builtin_amdgcn_s_setprio(0);
        }
    }
}

// Layer transition: xb[i][d] = agg*rden + bias[d], packed b64 writes.
__device__ __forceinline__ void trans_phase(const f32x4 (&acc)[8][2], const float (&rden)[4][2],
                                            const float* bias, short* xb, int c, int q)
{
    #pragma unroll
    for (int mt = 0; mt < 8; ++mt) {
        f32x4 bv = *(const f32x4*)&bias[mt*16 + q*4];
        #pragma unroll
        for (int nt = 0; nt < 2; ++nt) {
            float rd = rden[mt >> 1][nt];
            int ii = nt*16 + c;
            short4v o;
            #pragma unroll
            for (int r = 0; r < 4; ++r) o[r] = f2bf(fmaf(acc[mt][nt][r], rd, bv[r]));
            *(short4v*)&xb[ii*136 + mt*16 + q*4] = o;
        }
    }
}

// Layer-3 GEMM: packed cols [24 h | 8 score], NT=2; ht rows head-padded hd*16+dl,
// pad rows zero-filled (after A-frag preload frees the xb region).
__device__ __forceinline__ void gemm3_ht(short* buf, const short* __restrict__ wt,
                                         float* ss, int c, int q, int lane)
{
    const f32x4 zf = {0.f, 0.f, 0.f, 0.f};
    short8 afr[2][4];
    #pragma unroll
    for (int mt = 0; mt < 2; ++mt)
      #pragma unroll
      for (int kc = 0; kc < 4; ++kc)
        afr[mt][kc] = *(const short8*)&buf[(mt*16 + c)*136 + kc*32 + q*8];
    {   // zero-fill pad rows hd*16+dl, dl in 6..15 (40 rows x 8 granules)
        const short4v z4 = {0, 0, 0, 0};
        #pragma unroll
        for (int k = 0; k < 5; ++k) {
            int flat = lane + k*64;
            int z = flat >> 3, gg = flat & 7;
            int row = (z/10)*16 + 6 + (z%10);
            *(short4v*)&buf[row*32 + gg*4] = z4;
        }
    }
    #pragma unroll
    for (int nt = 0; nt < 2; ++nt) {
        short8 bfr[4];
        #pragma unroll
        for (int kc = 0; kc < 4; ++kc)
            bfr[kc] = *(const short8*)&wt[((nt*4 + kc)*16 + c)*32 + q*8];
        f32x4 a0 = zf, a1 = zf;
        __builtin_amdgcn_s_setprio(1);
        #pragma unroll
        for (int kc = 0; kc < 4; ++kc) {
            a0 = MFMA16(afr[0][kc], bfr[kc], a0);
            a1 = MFMA16(afr[1][kc], bfr[kc], a1);
        }
        __builtin_amdgcn_s_setprio(0);
        int p = nt*16 + c;
        if (p < 24) {
            int row = (p/6)*16 + (p%6);
            int sw3 = (row & 15) >> 1;
            short4v h0, h1;
            #pragma unroll
            for (int r = 0; r < 4; ++r) { h0[r] = f2bf(a0[r]); h1[r] = f2bf(a1[r]); }
            *(short4v*)&buf[row*32 + ((q ^ sw3))*4]     = h0;
            *(short4v*)&buf[row*32 + (((4+q) ^ sw3))*4] = h1;
        } else if (c >= 8) {   // score cols
            *(f32x4*)&ss[(c-8)*32 + q*4]      = a0;
            *(f32x4*)&ss[(c-8)*32 + 16 + q*4] = a1;
        }
    }
}

// Layer-3 aggregation with P as A-operand + in-register node-mean -> mcol[24].
__device__ __forceinline__ void agg3_mean(const short* buf, const float* ss,
                                          const float* b3, float* mcol, int c, int q)
{
    const f32x4 zf = {0.f, 0.f, 0.f, 0.f};
    int sw = c >> 1;
    float vout[4];
    #pragma unroll
    for (int hd = 0; hd < 4; ++hd) {
        f32x4 v0 = *(const f32x4*)&ss[hd*32 + q*8];
        f32x4 v1 = *(const f32x4*)&ss[hd*32 + q*8 + 4];
        short8 pf[2];
        #pragma unroll
        for (int it = 0; it < 2; ++it) {
            float sd = ss[(4+hd)*32 + it*16 + c];
            float pv[8]; float den = 0.f;
            #pragma unroll
            for (int v = 0; v < 8; ++v) {
                float sj = (v < 4) ? v0[v] : v1[v-4];
                float e = sd + sj; e = fmaxf(e, 0.2f*e);
                pv[v] = fexp2(e);
                den += pv[v];
            }
            den += __shfl_xor(den, 16, 64);
            den += __shfl_xor(den, 32, 64);
            float rd = frcp(den);
            short8 t;
            #pragma unroll
            for (int v = 0; v < 8; ++v) t[v] = f2bf(pv[v] * rd);
            pf[it] = t;
        }
        int rl = hd*16 + c;
        short4v lo = *(const short4v*)&buf[rl*32 + ((2*q)   ^ sw)*4];
        short4v hi = *(const short4v*)&buf[rl*32 + ((2*q+1) ^ sw)*4];
        short8 bf_ = __builtin_shufflevector(lo, hi, 0,1,2,3,4,5,6,7);
        __builtin_amdgcn_s_setprio(1);
        f32x4 o0 = MFMA16(pf[0], bf_, zf);   // D: row=i(4q+r), col=dl(c) in head hd
        f32x4 o1 = MFMA16(pf[1], bf_, zf);
        __builtin_amdgcn_s_setprio(0);
        float s = (o0[0]+o0[1]) + (o0[2]+o0[3]) + (o1[0]+o1[1]) + (o1[2]+o1[3]);
        s += __shfl_xor(s, 16, 64);
        s += __shfl_xor(s, 32, 64);
        vout[hd] = s;
    }
    if (q == 0 && c < 6) {
        #pragma unroll
        for (int hd = 0; hd < 4; ++hd)
            mcol[hd*6 + c] = vout[hd] * (1.f/32.f) + b3[hd*6 + c];
    }
}

__global__ __launch_bounds__(256, 4) void gat_mfma(
    const float* __restrict__ xs, const float* __restrict__ pe,
    const short* __restrict__ ws,
    const float* __restrict__ b1, const float* __restrict__ b2, const float* __restrict__ b3,
    const float* __restrict__ LW, const float* __restrict__ lb,
    float* __restrict__ out, int R)
{
    __shared__ short buf[4][4352];      // per-wave union: xb[32][136] <-> ht[*][32] (swz)
    __shared__ float ssx[4][256];       // [8][32] scores; mcol aliases [0..23]

    int t = threadIdx.x;
    int w = t >> 6, lane = t & 63;
    int c = lane & 15, q = lane >> 4;
    int g = blockIdx.x * 4 + w;
    int b = g / R;

    short* xb = buf[w];
    float* ss = ssx[w];

    // ---- build x0 [32][16] bf16 (cols 16..31 zero-padded for K=32 MFMA) ----
    {
        int j = lane >> 1, half = lane & 1;
        float v[8];
        if (half == 0) {
            v[0] = xs[g*32 + j];
            #pragma unroll
            for (int kk = 0; kk < 7; ++kk) v[1+kk] = pe[b*480 + j*15 + kk];
        } else {
            #pragma unroll
            for (int kk = 0; kk < 8; ++kk) v[kk] = pe[b*480 + j*15 + 7 + kk];
        }
        short8 px;
        #pragma unroll
        for (int kk = 0; kk < 8; ++kk) px[kk] = f2bf(v[kk]);
        *(short8*)&xb[j*136 + half*8] = px;
        *(short8*)&xb[j*136 + 16 + half*8] = (short8){0,0,0,0,0,0,0,0};
    }

    const short* wt1 = ws;
    const short* wt2 = ws + 4608;
    const short* wt3 = ws + 23040;

    // ================= layer 1 (K=16 padded to 32) =================
    {
        gemm_ht<1,9,8>(xb, wt1, ss, c, q);
        f32x4 acc[8][2]; float rden[4][2];
        agg12(xb, ss, c, q, acc, rden);
        trans_phase(acc, rden, b1, xb, c, q);
    }
    // ================= layer 2 (K=128) =============================
    {
        gemm_ht<4,9,8>(xb, wt2, ss, c, q);
        f32x4 acc[8][2]; float rden[4][2];
        agg12(xb, ss, c, q, acc, rden);
        trans_phase(acc, rden, b2, xb, c, q);
    }
    // ================= layer 3 (packed 24+8, P-as-A agg, mean) =====
    {
        gemm3_ht(xb, wt3, ss, c, q, lane);
        agg3_mean(xb, ss, b3, ss, c, q);   // mcol aliases ss[0..23]
    }
    // ---- epilogue: out[g] = mcol @ lin_w + lin_b (f32) ----
    {
        float o = lb[lane];
        #pragma unroll
        for (int cc = 0; cc < 24; ++cc)
            o = fmaf(ss[cc], LW[cc*64 + lane], o);
        out[g*64 + lane] = o;
    }
}

extern "C" void kernel_launch(void* const* d_in, const int* in_sizes, int n_in,
                              void* d_out, int out_size, void* d_ws, size_t ws_size,
                              hipStream_t stream) {
    const float* xs  = (const float*)d_in[0];
    const float* pe  = (const float*)d_in[1];
    const float* W1  = (const float*)d_in[2];
    const float* as1 = (const float*)d_in[3];
    const float* ad1 = (const float*)d_in[4];
    const float* b1  = (const float*)d_in[5];
    const float* W2  = (const float*)d_in[6];
    const float* as2 = (const float*)d_in[7];
    const float* ad2 = (const float*)d_in[8];
    const float* b2  = (const float*)d_in[9];
    const float* W3  = (const float*)d_in[10];
    const float* as3 = (const float*)d_in[11];
    const float* ad3 = (const float*)d_in[12];
    const float* b3  = (const float*)d_in[13];
    const float* LW  = (const float*)d_in[14];
    const float* lb  = (const float*)d_in[15];
    float* o = (float*)d_out;
    short* ws = (short*)d_ws;

    int G = in_sizes[0] / 32;       // B*R graphs (16384)
    int B = in_sizes[1] / 480;      // pos_enc = B*32*15
    int R = G / B;

    build_wt<<<dim3(106), dim3(256), 0, stream>>>(W1, as1, ad1, W2, as2, ad2,
                                                  W3, as3, ad3, ws);
    gat_mfma<<<dim3(G/4), dim3(256), 0, stream>>>(xs, pe, ws, b1, b2, b3, LW, lb, o, R);
}

// Round 11
// 93.469 us; speedup vs baseline: 1.3079x; 1.0169x over previous
//
#include <hip/hip_runtime.h>
#include <hip/hip_bf16.h>

// GNN2: 3-layer GAT over 16384 independent 32-node cliques.
// One WAVE per graph (4 graphs / 256-thread block), zero barriers.
// mfma_f32_16x16x32_bf16 for GEMMs + aggregation; scores fused into the GEMM
// via pre-multiplied Wa = W @ [a_src|a_dst] columns pre-scaled by log2(e)
// (exp2-domain softmax, no max-subtraction). f32 accumulate.
// r10 + (a) register double-buffered B-frag prefetch (hide L2 latency of wt
// loads), (b) layer-1 bias folded into K-pad col 16 (exact: sum(alpha)=1).

typedef __attribute__((ext_vector_type(8))) short short8;
typedef __attribute__((ext_vector_type(4))) short short4v;
typedef __attribute__((ext_vector_type(4))) float f32x4;

#define MFMA16(a,b,c) __builtin_amdgcn_mfma_f32_16x16x32_bf16(a,b,c,0,0,0)
#define L2E 1.4426950408889634f

__device__ __forceinline__ short f2bf(float f) {
    __hip_bfloat16 h = __float2bfloat16(f);
    return *reinterpret_cast<short*>(&h);
}
__device__ __forceinline__ float fexp2(float x) { return __builtin_amdgcn_exp2f(x); }
__device__ __forceinline__ float frcp(float x) {
    float r;
    asm volatile("v_rcp_f32 %0, %1" : "=v"(r) : "v"(x));
    return r;
}

// ---------------- pre-kernel: tiled transposed bf16 weights in ws ----------------
//  wt1 [0,4608):       NT=9, KC=1. n<128: k<16 -> W1[k][n], k==16 -> b1[n], else 0;
//                      n in 128..135 -> L2E*Wa1 (k<16 only); else 0
//  wt2 [4608,23040):   NT=9, KC=4. W2/Wa2
//  wt3 [23040,27136):  NT=2, KC=4. n<24 -> W3[k][n] (packed hd*6+dl); 24..31 -> L2E*Wa3
__global__ __launch_bounds__(256) void build_wt(
    const float* __restrict__ W1, const float* __restrict__ as1, const float* __restrict__ ad1,
    const float* __restrict__ B1,
    const float* __restrict__ W2, const float* __restrict__ as2, const float* __restrict__ ad2,
    const float* __restrict__ W3, const float* __restrict__ as3, const float* __restrict__ ad3,
    short* __restrict__ ws)
{
    int i = blockIdx.x * 256 + threadIdx.x;
    float val = 0.f;
    if (i < 4608) {                       // layer 1 (KC=1 -> [n][k])
        int n = i >> 5, k = i & 31;
        if (k < 16) {
            if (n < 128) val = W1[k*128 + n];
            else if (n < 136) {
                int cc = n - 128; const float* a = (cc < 4) ? as1 : ad1;
                for (int dl = 0; dl < 32; ++dl)
                    val += W1[k*128 + (cc&3)*32 + dl] * a[(cc&3)*32 + dl];
                val *= L2E;
            }
        } else if (k == 16 && n < 128) {
            val = B1[n];                  // bias row hit by constant-1 input col
        }
        ws[i] = f2bf(val);
    } else if (i < 23040) {               // layer 2
        int j = i - 4608;
        int kq = j & 31, c = (j >> 5) & 15, kc = (j >> 9) & 3, nt = j >> 11;
        int n = nt*16 + c, k = kc*32 + kq;
        if (n < 128) val = W2[k*128 + n];
        else if (n < 136) {
            int cc = n - 128; const float* a = (cc < 4) ? as2 : ad2;
            for (int dl = 0; dl < 32; ++dl)
                val += W2[k*128 + (cc&3)*32 + dl] * a[(cc&3)*32 + dl];
            val *= L2E;
        }
        ws[i] = f2bf(val);
    } else {                              // layer 3 (packed 24 + 8 score)
        int j = i - 23040;
        int kq = j & 31, c = (j >> 5) & 15, kc = (j >> 9) & 3, nt = j >> 11;
        int n = nt*16 + c, k = kc*32 + kq;
        if (n < 24) val = W3[k*24 + n];
        else {
            int cc = n - 24; const float* a = (cc < 4) ? as3 : ad3;
            for (int dl = 0; dl < 6; ++dl)
                val += W3[k*24 + (cc&3)*6 + dl] * a[(cc&3)*6 + dl];
            val *= L2E;
        }
        ws[i] = f2bf(val);
    }
}

// ---------------- main-kernel phases ----------------
// Fragment layout (gfx950 16x16x32 bf16): A: row=lane&15, k=8*(lane>>4)+v;
// B: col=lane&15, k=8*(lane>>4)+v; D: col=lane&15, row=4*(lane>>4)+r. [m89/m93]
// xb: [32][136] bf16. ht: [128][32] bf16 overlaid, 4-short granule gl of row d
// stored at gl ^ ((d&15)>>1). ss: f32[8][32] separate.

// GEMM + ht/score write, per-nt interleaved, B-frags double-buffered in regs.
template<int KC, int NT, int NTH>
__device__ __forceinline__ void gemm_ht(short* buf, const short* __restrict__ wt,
                                        float* ss, int c, int q)
{
    const f32x4 zf = {0.f, 0.f, 0.f, 0.f};
    short8 afr[2][KC];
    #pragma unroll
    for (int mt = 0; mt < 2; ++mt)
      #pragma unroll
      for (int kc = 0; kc < KC; ++kc)
        afr[mt][kc] = *(const short8*)&buf[(mt*16 + c)*136 + kc*32 + q*8];
    int sw = c >> 1;
    short8 bfr[2][KC];
    #pragma unroll
    for (int kc = 0; kc < KC; ++kc)
        bfr[0][kc] = *(const short8*)&wt[(kc*16 + c)*32 + q*8];
    #pragma unroll
    for (int nt = 0; nt < NT; ++nt) {
        const int cur = nt & 1, nxt = cur ^ 1;
        if (nt + 1 < NT) {
            #pragma unroll
            for (int kc = 0; kc < KC; ++kc)
                bfr[nxt][kc] = *(const short8*)&wt[(((nt+1)*KC + kc)*16 + c)*32 + q*8];
        }
        f32x4 a0 = zf, a1 = zf;
        __builtin_amdgcn_s_setprio(1);
        #pragma unroll
        for (int kc = 0; kc < KC; ++kc) {
            a0 = MFMA16(afr[0][kc], bfr[cur][kc], a0);
            a1 = MFMA16(afr[1][kc], bfr[cur][kc], a1);
        }
        __builtin_amdgcn_s_setprio(0);
        if (nt < NTH) {
            int d = nt*16 + c;
            short4v h0, h1;
            #pragma unroll
            for (int r = 0; r < 4; ++r) { h0[r] = f2bf(a0[r]); h1[r] = f2bf(a1[r]); }
            *(short4v*)&buf[d*32 + ((q ^ sw))*4]     = h0;
            *(short4v*)&buf[d*32 + (((4+q) ^ sw))*4] = h1;
        } else if (c < 8) {   // score tile: rows c<4 = s_src head c, c>=4 = s_dst
            *(f32x4*)&ss[c*32 + q*4]      = a0;
            *(f32x4*)&ss[c*32 + 16 + q*4] = a1;
        }
    }
}

// Fused frag+agg (layers 1-2): per head build P-frags (exp2 domain, no max-sub),
// then 2 MFMAs per M-tile.
__device__ __forceinline__ void agg12(const short* buf, const float* ss,
                                      int c, int q, f32x4 (&acc)[8][2], float (&rden)[4][2])
{
    const f32x4 zf = {0.f, 0.f, 0.f, 0.f};
    int sw = c >> 1;
    #pragma unroll
    for (int hd = 0; hd < 4; ++hd) {
        f32x4 v0 = *(const f32x4*)&ss[hd*32 + q*8];
        f32x4 v1 = *(const f32x4*)&ss[hd*32 + q*8 + 4];
        short8 pf[2];
        #pragma unroll
        for (int it = 0; it < 2; ++it) {
            float sd = ss[(4+hd)*32 + it*16 + c];
            float den = 0.f; short8 t;
            #pragma unroll
            for (int v = 0; v < 8; ++v) {
                float sj = (v < 4) ? v0[v] : v1[v-4];
                float e = sd + sj; e = fmaxf(e, 0.2f*e);   // lrelu, log2 domain
                float p = fexp2(e);
                den += p;
                t[v] = f2bf(p);
            }
            den += __shfl_xor(den, 16, 64);
            den += __shfl_xor(den, 32, 64);
            pf[it] = t; rden[hd][it] = frcp(den);
        }
        #pragma unroll
        for (int m2 = 0; m2 < 2; ++m2) {
            int mt = hd*2 + m2, d = mt*16 + c;
            short4v lo = *(const short4v*)&buf[d*32 + ((2*q)   ^ sw)*4];
            short4v hi = *(const short4v*)&buf[d*32 + ((2*q+1) ^ sw)*4];
            short8 af = __builtin_shufflevector(lo, hi, 0,1,2,3,4,5,6,7);
            __builtin_amdgcn_s_setprio(1);
            acc[mt][0] = MFMA16(af, pf[0], zf);
            acc[mt][1] = MFMA16(af, pf[1], zf);
            __builtin_amdgcn_s_setprio(0);
        }
    }
}

// Layer transition: xb[i][d] = agg*rden (+ bias), packed b64 writes.
template<bool BIAS>
__device__ __forceinline__ void trans_phase(const f32x4 (&acc)[8][2], const float (&rden)[4][2],
                                            const float* bias, short* xb, int c, int q)
{
    #pragma unroll
    for (int mt = 0; mt < 8; ++mt) {
        f32x4 bv;
        if (BIAS) bv = *(const f32x4*)&bias[mt*16 + q*4];
        #pragma unroll
        for (int nt = 0; nt < 2; ++nt) {
            float rd = rden[mt >> 1][nt];
            int ii = nt*16 + c;
            short4v o;
            #pragma unroll
            for (int r = 0; r < 4; ++r)
                o[r] = f2bf(BIAS ? fmaf(acc[mt][nt][r], rd, bv[r]) : acc[mt][nt][r] * rd);
            *(short4v*)&xb[ii*136 + mt*16 + q*4] = o;
        }
    }
}

// Layer-3 GEMM: packed cols [24 h | 8 score], NT=2; ht rows head-padded hd*16+dl,
// pad rows zero-filled (after A-frag preload frees the xb region).
__device__ __forceinline__ void gemm3_ht(short* buf, const short* __restrict__ wt,
                                         float* ss, int c, int q, int lane)
{
    const f32x4 zf = {0.f, 0.f, 0.f, 0.f};
    short8 afr[2][4];
    #pragma unroll
    for (int mt = 0; mt < 2; ++mt)
      #pragma unroll
      for (int kc = 0; kc < 4; ++kc)
        afr[mt][kc] = *(const short8*)&buf[(mt*16 + c)*136 + kc*32 + q*8];
    short8 bfr[2][4];
    #pragma unroll
    for (int kc = 0; kc < 4; ++kc)
        bfr[0][kc] = *(const short8*)&wt[(kc*16 + c)*32 + q*8];
    {   // zero-fill pad rows hd*16+dl, dl in 6..15 (40 rows x 8 granules)
        const short4v z4 = {0, 0, 0, 0};
        #pragma unroll
        for (int k = 0; k < 5; ++k) {
            int flat = lane + k*64;
            int z = flat >> 3, gg = flat & 7;
            int row = (z/10)*16 + 6 + (z%10);
            *(short4v*)&buf[row*32 + gg*4] = z4;
        }
    }
    #pragma unroll
    for (int nt = 0; nt < 2; ++nt) {
        const int cur = nt & 1, nxt = cur ^ 1;
        if (nt + 1 < 2) {
            #pragma unroll
            for (int kc = 0; kc < 4; ++kc)
                bfr[nxt][kc] = *(const short8*)&wt[(((nt+1)*4 + kc)*16 + c)*32 + q*8];
        }
        f32x4 a0 = zf, a1 = zf;
        __builtin_amdgcn_s_setprio(1);
        #pragma unroll
        for (int kc = 0; kc < 4; ++kc) {
            a0 = MFMA16(afr[0][kc], bfr[cur][kc], a0);
            a1 = MFMA16(afr[1][kc], bfr[cur][kc], a1);
        }
        __builtin_amdgcn_s_setprio(0);
        int p = nt*16 + c;
        if (p < 24) {
            int row = (p/6)*16 + (p%6);
            int sw3 = (row & 15) >> 1;
            short4v h0, h1;
            #pragma unroll
            for (int r = 0; r < 4; ++r) { h0[r] = f2bf(a0[r]); h1[r] = f2bf(a1[r]); }
            *(short4v*)&buf[row*32 + ((q ^ sw3))*4]     = h0;
            *(short4v*)&buf[row*32 + (((4+q) ^ sw3))*4] = h1;
        } else if (c >= 8) {   // score cols
            *(f32x4*)&ss[(c-8)*32 + q*4]      = a0;
            *(f32x4*)&ss[(c-8)*32 + 16 + q*4] = a1;
        }
    }
}

// Layer-3 aggregation with P as A-operand + in-register node-mean -> mcol[24].
__device__ __forceinline__ void agg3_mean(const short* buf, const float* ss,
                                          const float* b3, float* mcol, int c, int q)
{
    const f32x4 zf = {0.f, 0.f, 0.f, 0.f};
    int sw = c >> 1;
    float vout[4];
    #pragma unroll
    for (int hd = 0; hd < 4; ++hd) {
        f32x4 v0 = *(const f32x4*)&ss[hd*32 + q*8];
        f32x4 v1 = *(const f32x4*)&ss[hd*32 + q*8 + 4];
        short8 pf[2];
        #pragma unroll
        for (int it = 0; it < 2; ++it) {
            float sd = ss[(4+hd)*32 + it*16 + c];
            float pv[8]; float den = 0.f;
            #pragma unroll
            for (int v = 0; v < 8; ++v) {
                float sj = (v < 4) ? v0[v] : v1[v-4];
                float e = sd + sj; e = fmaxf(e, 0.2f*e);
                pv[v] = fexp2(e);
                den += pv[v];
            }
            den += __shfl_xor(den, 16, 64);
            den += __shfl_xor(den, 32, 64);
            float rd = frcp(den);
            short8 t;
            #pragma unroll
            for (int v = 0; v < 8; ++v) t[v] = f2bf(pv[v] * rd);
            pf[it] = t;
        }
        int rl = hd*16 + c;
        short4v lo = *(const short4v*)&buf[rl*32 + ((2*q)   ^ sw)*4];
        short4v hi = *(const short4v*)&buf[rl*32 + ((2*q+1) ^ sw)*4];
        short8 bf_ = __builtin_shufflevector(lo, hi, 0,1,2,3,4,5,6,7);
        __builtin_amdgcn_s_setprio(1);
        f32x4 o0 = MFMA16(pf[0], bf_, zf);   // D: row=i(4q+r), col=dl(c) in head hd
        f32x4 o1 = MFMA16(pf[1], bf_, zf);
        __builtin_amdgcn_s_setprio(0);
        float s = (o0[0]+o0[1]) + (o0[2]+o0[3]) + (o1[0]+o1[1]) + (o1[2]+o1[3]);
        s += __shfl_xor(s, 16, 64);
        s += __shfl_xor(s, 32, 64);
        vout[hd] = s;
    }
    if (q == 0 && c < 6) {
        #pragma unroll
        for (int hd = 0; hd < 4; ++hd)
            mcol[hd*6 + c] = vout[hd] * (1.f/32.f) + b3[hd*6 + c];
    }
}

__global__ __launch_bounds__(256, 4) void gat_mfma(
    const float* __restrict__ xs, const float* __restrict__ pe,
    const short* __restrict__ ws,
    const float* __restrict__ b2, const float* __restrict__ b3,
    const float* __restrict__ LW, const float* __restrict__ lb,
    float* __restrict__ out, int R)
{
    __shared__ short buf[4][4352];      // per-wave union: xb[32][136] <-> ht[*][32] (swz)
    __shared__ float ssx[4][256];       // [8][32] scores; mcol aliases [0..23]

    int t = threadIdx.x;
    int w = t >> 6, lane = t & 63;
    int c = lane & 15, q = lane >> 4;
    int g = blockIdx.x * 4 + w;
    int b = g / R;

    short* xb = buf[w];
    float* ss = ssx[w];

    // ---- build x0 [32][16] bf16; col 16 = 1.0 (bias row), 17..31 = 0 ----
    {
        int j = lane >> 1, half = lane & 1;
        float v[8];
        if (half == 0) {
            v[0] = xs[g*32 + j];
            #pragma unroll
            for (int kk = 0; kk < 7; ++kk) v[1+kk] = pe[b*480 + j*15 + kk];
        } else {
            #pragma unroll
            for (int kk = 0; kk < 8; ++kk) v[kk] = pe[b*480 + j*15 + 7 + kk];
        }
        short8 px;
        #pragma unroll
        for (int kk = 0; kk < 8; ++kk) px[kk] = f2bf(v[kk]);
        *(short8*)&xb[j*136 + half*8] = px;
        short8 pad = {0,0,0,0,0,0,0,0};
        if (half == 0) pad[0] = (short)0x3F80;       // bf16(1.0) at col 16
        *(short8*)&xb[j*136 + 16 + half*8] = pad;
    }

    const short* wt1 = ws;
    const short* wt2 = ws + 4608;
    const short* wt3 = ws + 23040;

    // ================= layer 1 (K=16 padded to 32; bias folded) ====
    {
        gemm_ht<1,9,8>(xb, wt1, ss, c, q);
        f32x4 acc[8][2]; float rden[4][2];
        agg12(xb, ss, c, q, acc, rden);
        trans_phase<false>(acc, rden, nullptr, xb, c, q);
    }
    // ================= layer 2 (K=128) =============================
    {
        gemm_ht<4,9,8>(xb, wt2, ss, c, q);
        f32x4 acc[8][2]; float rden[4][2];
        agg12(xb, ss, c, q, acc, rden);
        trans_phase<true>(acc, rden, b2, xb, c, q);
    }
    // ================= layer 3 (packed 24+8, P-as-A agg, mean) =====
    {
        gemm3_ht(xb, wt3, ss, c, q, lane);
        agg3_mean(xb, ss, b3, ss, c, q);   // mcol aliases ss[0..23]
    }
    // ---- epilogue: out[g] = mcol @ lin_w + lin_b (f32) ----
    {
        float o = lb[lane];
        #pragma unroll
        for (int cc = 0; cc < 24; ++cc)
            o = fmaf(ss[cc], LW[cc*64 + lane], o);
        out[g*64 + lane] = o;
    }
}

extern "C" void kernel_launch(void* const* d_in, const int* in_sizes, int n_in,
                              void* d_out, int out_size, void* d_ws, size_t ws_size,
                              hipStream_t stream) {
    const float* xs  = (const float*)d_in[0];
    const float* pe  = (const float*)d_in[1];
    const float* W1  = (const float*)d_in[2];
    const float* as1 = (const float*)d_in[3];
    const float* ad1 = (const float*)d_in[4];
    const float* b1  = (const float*)d_in[5];
    const float* W2  = (const float*)d_in[6];
    const float* as2 = (const float*)d_in[7];
    const float* ad2 = (const float*)d_in[8];
    const float* b2  = (const float*)d_in[9];
    const float* W3  = (const float*)d_in[10];
    const float* as3 = (const float*)d_in[11];
    const float* ad3 = (const float*)d_in[12];
    const float* b3  = (const float*)d_in[13];
    const float* LW  = (const float*)d_in[14];
    const float* lb  = (const float*)d_in[15];
    float* o = (float*)d_out;
    short* ws = (short*)d_ws;

    int G = in_sizes[0] / 32;       // B*R graphs (16384)
    int B = in_sizes[1] / 480;      // pos_enc = B*32*15
    int R = G / B;

    build_wt<<<dim3(106), dim3(256), 0, stream>>>(W1, as1, ad1, b1, W2, as2, ad2,
                                                  W3, as3, ad3, ws);
    gat_mfma<<<dim3(G/4), dim3(256), 0, stream>>>(xs, pe, ws, b2, b3, LW, lb, o, R);
}

// Round 13
// 87.678 us; speedup vs baseline: 1.3943x; 1.0660x over previous
//
#include <hip/hip_runtime.h>
#include <hip/hip_bf16.h>

// GNN2: 3-layer GAT over 16384 independent 32-node cliques.
// One WAVE per graph (4 graphs / 256-thread block), zero barriers.
// mfma_f32_16x16x32_bf16 for GEMMs + aggregation; scores fused into the GEMM
// via pre-multiplied Wa = W @ [a_src|a_dst] columns pre-scaled by log2(e)
// (exp2-domain softmax, no max-subtraction). f32 accumulate.
// r11 + P-build arithmetic on f32x2 vectors (packed v_pk_add/mul_f32 VALU).

typedef __attribute__((ext_vector_type(8))) short short8;
typedef __attribute__((ext_vector_type(4))) short short4v;
typedef __attribute__((ext_vector_type(4))) float f32x4;
typedef __attribute__((ext_vector_type(2))) float f32x2;

#define MFMA16(a,b,c) __builtin_amdgcn_mfma_f32_16x16x32_bf16(a,b,c,0,0,0)
#define L2E 1.4426950408889634f

__device__ __forceinline__ short f2bf(float f) {
    __hip_bfloat16 h = __float2bfloat16(f);
    return *reinterpret_cast<short*>(&h);
}
__device__ __forceinline__ float bf2f(short s) {
    unsigned int u = ((unsigned int)(unsigned short)s) << 16;
    return __builtin_bit_cast(float, u);
}
__device__ __forceinline__ float fexp2(float x) { return __builtin_amdgcn_exp2f(x); }
__device__ __forceinline__ float frcp(float x) {
    float r;
    asm volatile("v_rcp_f32 %0, %1" : "=v"(r) : "v"(x));
    return r;
}

// P-build for one (head, i-tile): e = lrelu(sd + sj) in log2 domain (packed f32x2
// adds/muls), p = exp2(e); returns unnormalized bf16 P-frag + 1/den.
__device__ __forceinline__ void pbuild(float sd, const f32x4 v0, const f32x4 v1,
                                       short8& t, float& rd)
{
    f32x2 sd2; sd2[0] = sd; sd2[1] = sd;
    f32x2 a0 = __builtin_shufflevector(v0, v0, 0, 1) + sd2;
    f32x2 a1 = __builtin_shufflevector(v0, v0, 2, 3) + sd2;
    f32x2 a2 = __builtin_shufflevector(v1, v1, 0, 1) + sd2;
    f32x2 a3 = __builtin_shufflevector(v1, v1, 2, 3) + sd2;
    a0 = __builtin_elementwise_max(a0, a0 * 0.2f);   // lrelu (log2 domain)
    a1 = __builtin_elementwise_max(a1, a1 * 0.2f);
    a2 = __builtin_elementwise_max(a2, a2 * 0.2f);
    a3 = __builtin_elementwise_max(a3, a3 * 0.2f);
    float p0 = fexp2(a0[0]), p1 = fexp2(a0[1]);
    float p2 = fexp2(a1[0]), p3 = fexp2(a1[1]);
    float p4 = fexp2(a2[0]), p5 = fexp2(a2[1]);
    float p6 = fexp2(a3[0]), p7 = fexp2(a3[1]);
    t[0] = f2bf(p0); t[1] = f2bf(p1); t[2] = f2bf(p2); t[3] = f2bf(p3);
    t[4] = f2bf(p4); t[5] = f2bf(p5); t[6] = f2bf(p6); t[7] = f2bf(p7);
    float den = ((p0 + p1) + (p2 + p3)) + ((p4 + p5) + (p6 + p7));
    den += __shfl_xor(den, 16, 64);
    den += __shfl_xor(den, 32, 64);
    rd = frcp(den);
}

// ---------------- pre-kernel: tiled transposed bf16 weights in ws ----------------
//  wt1 [0,4608):       NT=9, KC=1. n<128: k<16 -> W1[k][n], k==16 -> b1[n], else 0;
//                      n in 128..135 -> L2E*Wa1 (k<16 only); else 0
//  wt2 [4608,23040):   NT=9, KC=4. W2/Wa2
//  wt3 [23040,27136):  NT=2, KC=4. n<24 -> W3[k][n] (packed hd*6+dl); 24..31 -> L2E*Wa3
__global__ __launch_bounds__(256) void build_wt(
    const float* __restrict__ W1, const float* __restrict__ as1, const float* __restrict__ ad1,
    const float* __restrict__ B1,
    const float* __restrict__ W2, const float* __restrict__ as2, const float* __restrict__ ad2,
    const float* __restrict__ W3, const float* __restrict__ as3, const float* __restrict__ ad3,
    short* __restrict__ ws)
{
    int i = blockIdx.x * 256 + threadIdx.x;
    float val = 0.f;
    if (i < 4608) {                       // layer 1 (KC=1 -> [n][k])
        int n = i >> 5, k = i & 31;
        if (k < 16) {
            if (n < 128) val = W1[k*128 + n];
            else if (n < 136) {
                int cc = n - 128; const float* a = (cc < 4) ? as1 : ad1;
                for (int dl = 0; dl < 32; ++dl)
                    val += W1[k*128 + (cc&3)*32 + dl] * a[(cc&3)*32 + dl];
                val *= L2E;
            }
        } else if (k == 16 && n < 128) {
            val = B1[n];                  // bias row hit by constant-1 input col
        }
        ws[i] = f2bf(val);
    } else if (i < 23040) {               // layer 2
        int j = i - 4608;
        int kq = j & 31, c = (j >> 5) & 15, kc = (j >> 9) & 3, nt = j >> 11;
        int n = nt*16 + c, k = kc*32 + kq;
        if (n < 128) val = W2[k*128 + n];
        else if (n < 136) {
            int cc = n - 128; const float* a = (cc < 4) ? as2 : ad2;
            for (int dl = 0; dl < 32; ++dl)
                val += W2[k*128 + (cc&3)*32 + dl] * a[(cc&3)*32 + dl];
            val *= L2E;
        }
        ws[i] = f2bf(val);
    } else {                              // layer 3 (packed 24 + 8 score)
        int j = i - 23040;
        int kq = j & 31, c = (j >> 5) & 15, kc = (j >> 9) & 3, nt = j >> 11;
        int n = nt*16 + c, k = kc*32 + kq;
        if (n < 24) val = W3[k*24 + n];
        else {
            int cc = n - 24; const float* a = (cc < 4) ? as3 : ad3;
            for (int dl = 0; dl < 6; ++dl)
                val += W3[k*24 + (cc&3)*6 + dl] * a[(cc&3)*6 + dl];
            val *= L2E;
        }
        ws[i] = f2bf(val);
    }
}

// ---------------- main-kernel phases ----------------
// Fragment layout (gfx950 16x16x32 bf16): A: row=lane&15, k=8*(lane>>4)+v;
// B: col=lane&15, k=8*(lane>>4)+v; D: col=lane&15, row=4*(lane>>4)+r. [m89/m93]
// xb: [32][136] bf16. ht: [128][32] bf16 overlaid, 4-short granule gl of row d
// stored at gl ^ ((d&15)>>1). ss: f32[8][32] separate.

// GEMM + ht/score write, per-nt interleaved, B-frags double-buffered in regs.
template<int KC, int NT, int NTH>
__device__ __forceinline__ void gemm_ht(short* buf, const short* __restrict__ wt,
                                        float* ss, int c, int q)
{
    const f32x4 zf = {0.f, 0.f, 0.f, 0.f};
    short8 afr[2][KC];
    #pragma unroll
    for (int mt = 0; mt < 2; ++mt)
      #pragma unroll
      for (int kc = 0; kc < KC; ++kc)
        afr[mt][kc] = *(const short8*)&buf[(mt*16 + c)*136 + kc*32 + q*8];
    int sw = c >> 1;
    short8 bfr[2][KC];
    #pragma unroll
    for (int kc = 0; kc < KC; ++kc)
        bfr[0][kc] = *(const short8*)&wt[(kc*16 + c)*32 + q*8];
    #pragma unroll
    for (int nt = 0; nt < NT; ++nt) {
        const int cur = nt & 1, nxt = cur ^ 1;
        if (nt + 1 < NT) {
            #pragma unroll
            for (int kc = 0; kc < KC; ++kc)
                bfr[nxt][kc] = *(const short8*)&wt[(((nt+1)*KC + kc)*16 + c)*32 + q*8];
        }
        f32x4 a0 = zf, a1 = zf;
        __builtin_amdgcn_s_setprio(1);
        #pragma unroll
        for (int kc = 0; kc < KC; ++kc) {
            a0 = MFMA16(afr[0][kc], bfr[cur][kc], a0);
            a1 = MFMA16(afr[1][kc], bfr[cur][kc], a1);
        }
        __builtin_amdgcn_s_setprio(0);
        if (nt < NTH) {
            int d = nt*16 + c;
            short4v h0, h1;
            #pragma unroll
            for (int r = 0; r < 4; ++r) { h0[r] = f2bf(a0[r]); h1[r] = f2bf(a1[r]); }
            *(short4v*)&buf[d*32 + ((q ^ sw))*4]     = h0;
            *(short4v*)&buf[d*32 + (((4+q) ^ sw))*4] = h1;
        } else if (c < 8) {   // score tile: rows c<4 = s_src head c, c>=4 = s_dst
            *(f32x4*)&ss[c*32 + q*4]      = a0;
            *(f32x4*)&ss[c*32 + 16 + q*4] = a1;
        }
    }
}

// Fused frag+agg (layers 1-2): per head build P-frags (packed pbuild), then
// 2 MFMAs per M-tile.
__device__ __forceinline__ void agg12(const short* buf, const float* ss,
                                      int c, int q, f32x4 (&acc)[8][2], float (&rden)[4][2])
{
    const f32x4 zf = {0.f, 0.f, 0.f, 0.f};
    int sw = c >> 1;
    #pragma unroll
    for (int hd = 0; hd < 4; ++hd) {
        f32x4 v0 = *(const f32x4*)&ss[hd*32 + q*8];
        f32x4 v1 = *(const f32x4*)&ss[hd*32 + q*8 + 4];
        short8 pf[2];
        #pragma unroll
        for (int it = 0; it < 2; ++it) {
            float sd = ss[(4+hd)*32 + it*16 + c];
            pbuild(sd, v0, v1, pf[it], rden[hd][it]);
        }
        #pragma unroll
        for (int m2 = 0; m2 < 2; ++m2) {
            int mt = hd*2 + m2, d = mt*16 + c;
            short4v lo = *(const short4v*)&buf[d*32 + ((2*q)   ^ sw)*4];
            short4v hi = *(const short4v*)&buf[d*32 + ((2*q+1) ^ sw)*4];
            short8 af = __builtin_shufflevector(lo, hi, 0,1,2,3,4,5,6,7);
            __builtin_amdgcn_s_setprio(1);
            acc[mt][0] = MFMA16(af, pf[0], zf);
            acc[mt][1] = MFMA16(af, pf[1], zf);
            __builtin_amdgcn_s_setprio(0);
        }
    }
}

// Layer transition: xb[i][d] = agg*rden (+ bias), packed b64 writes.
template<bool BIAS>
__device__ __forceinline__ void trans_phase(const f32x4 (&acc)[8][2], const float (&rden)[4][2],
                                            const float* bias, short* xb, int c, int q)
{
    #pragma unroll
    for (int mt = 0; mt < 8; ++mt) {
        f32x4 bv;
        if (BIAS) bv = *(const f32x4*)&bias[mt*16 + q*4];
        #pragma unroll
        for (int nt = 0; nt < 2; ++nt) {
            float rd = rden[mt >> 1][nt];
            int ii = nt*16 + c;
            short4v o;
            #pragma unroll
            for (int r = 0; r < 4; ++r)
                o[r] = f2bf(BIAS ? fmaf(acc[mt][nt][r], rd, bv[r]) : acc[mt][nt][r] * rd);
            *(short4v*)&xb[ii*136 + mt*16 + q*4] = o;
        }
    }
}

// Layer-3 GEMM: packed cols [24 h | 8 score], NT=2; ht rows head-padded hd*16+dl,
// pad rows zero-filled (after A-frag preload frees the xb region).
__device__ __forceinline__ void gemm3_ht(short* buf, const short* __restrict__ wt,
                                         float* ss, int c, int q, int lane)
{
    const f32x4 zf = {0.f, 0.f, 0.f, 0.f};
    short8 afr[2][4];
    #pragma unroll
    for (int mt = 0; mt < 2; ++mt)
      #pragma unroll
      for (int kc = 0; kc < 4; ++kc)
        afr[mt][kc] = *(const short8*)&buf[(mt*16 + c)*136 + kc*32 + q*8];
    short8 bfr[2][4];
    #pragma unroll
    for (int kc = 0; kc < 4; ++kc)
        bfr[0][kc] = *(const short8*)&wt[(kc*16 + c)*32 + q*8];
    {   // zero-fill pad rows hd*16+dl, dl in 6..15 (40 rows x 8 granules)
        const short4v z4 = {0, 0, 0, 0};
        #pragma unroll
        for (int k = 0; k < 5; ++k) {
            int flat = lane + k*64;
            int z = flat >> 3, gg = flat & 7;
            int row = (z/10)*16 + 6 + (z%10);
            *(short4v*)&buf[row*32 + gg*4] = z4;
        }
    }
    #pragma unroll
    for (int nt = 0; nt < 2; ++nt) {
        const int cur = nt & 1, nxt = cur ^ 1;
        if (nt + 1 < 2) {
            #pragma unroll
            for (int kc = 0; kc < 4; ++kc)
                bfr[nxt][kc] = *(const short8*)&wt[(((nt+1)*4 + kc)*16 + c)*32 + q*8];
        }
        f32x4 a0 = zf, a1 = zf;
        __builtin_amdgcn_s_setprio(1);
        #pragma unroll
        for (int kc = 0; kc < 4; ++kc) {
            a0 = MFMA16(afr[0][kc], bfr[cur][kc], a0);
            a1 = MFMA16(afr[1][kc], bfr[cur][kc], a1);
        }
        __builtin_amdgcn_s_setprio(0);
        int p = nt*16 + c;
        if (p < 24) {
            int row = (p/6)*16 + (p%6);
            int sw3 = (row & 15) >> 1;
            short4v h0, h1;
            #pragma unroll
            for (int r = 0; r < 4; ++r) { h0[r] = f2bf(a0[r]); h1[r] = f2bf(a1[r]); }
            *(short4v*)&buf[row*32 + ((q ^ sw3))*4]     = h0;
            *(short4v*)&buf[row*32 + (((4+q) ^ sw3))*4] = h1;
        } else if (c >= 8) {   // score cols
            *(f32x4*)&ss[(c-8)*32 + q*4]      = a0;
            *(f32x4*)&ss[(c-8)*32 + 16 + q*4] = a1;
        }
    }
}

// Layer-3 aggregation with P as A-operand + in-register node-mean -> mcol[24].
__device__ __forceinline__ void agg3_mean(const short* buf, const float* ss,
                                          const float* b3, float* mcol, int c, int q)
{
    const f32x4 zf = {0.f, 0.f, 0.f, 0.f};
    int sw = c >> 1;
    float vout[4];
    #pragma unroll
    for (int hd = 0; hd < 4; ++hd) {
        f32x4 v0 = *(const f32x4*)&ss[hd*32 + q*8];
        f32x4 v1 = *(const f32x4*)&ss[hd*32 + q*8 + 4];
        short8 pf[2];
        #pragma unroll
        for (int it = 0; it < 2; ++it) {
            float sd = ss[(4+hd)*32 + it*16 + c];
            float rd;
            short8 t;
            pbuild(sd, v0, v1, t, rd);
            #pragma unroll
            for (int v = 0; v < 8; ++v)
                t[v] = f2bf(bf2f(t[v]) * rd);
            pf[it] = t;
        }
        int rl = hd*16 + c;
        short4v lo = *(const short4v*)&buf[rl*32 + ((2*q)   ^ sw)*4];
        short4v hi = *(const short4v*)&buf[rl*32 + ((2*q+1) ^ sw)*4];
        short8 bf_ = __builtin_shufflevector(lo, hi, 0,1,2,3,4,5,6,7);
        __builtin_amdgcn_s_setprio(1);
        f32x4 o0 = MFMA16(pf[0], bf_, zf);   // D: row=i(4q+r), col=dl(c) in head hd
        f32x4 o1 = MFMA16(pf[1], bf_, zf);
        __builtin_amdgcn_s_setprio(0);
        float s = (o0[0]+o0[1]) + (o0[2]+o0[3]) + (o1[0]+o1[1]) + (o1[2]+o1[3]);
        s += __shfl_xor(s, 16, 64);
        s += __shfl_xor(s, 32, 64);
        vout[hd] = s;
    }
    if (q == 0 && c < 6) {
        #pragma unroll
        for (int hd = 0; hd < 4; ++hd)
            mcol[hd*6 + c] = vout[hd] * (1.f/32.f) + b3[hd*6 + c];
    }
}

__global__ __launch_bounds__(256, 4) void gat_mfma(
    const float* __restrict__ xs, const float* __restrict__ pe,
    const short* __restrict__ ws,
    const float* __restrict__ b2, const float* __restrict__ b3,
    const float* __restrict__ LW, const float* __restrict__ lb,
    float* __restrict__ out, int R)
{
    __shared__ short buf[4][4352];      // per-wave union: xb[32][136] <-> ht[*][32] (swz)
    __shared__ float ssx[4][256];       // [8][32] scores; mcol aliases [0..23]

    int t = threadIdx.x;
    int w = t >> 6, lane = t & 63;
    int c = lane & 15, q = lane >> 4;
    int g = blockIdx.x * 4 + w;
    int b = g / R;

    short* xb = buf[w];
    float* ss = ssx[w];

    // ---- build x0 [32][16] bf16; col 16 = 1.0 (bias row), 17..31 = 0 ----
    {
        int j = lane >> 1, half = lane & 1;
        float v[8];
        if (half == 0) {
            v[0] = xs[g*32 + j];
            #pragma unroll
            for (int kk = 0; kk < 7; ++kk) v[1+kk] = pe[b*480 + j*15 + kk];
        } else {
            #pragma unroll
            for (int kk = 0; kk < 8; ++kk) v[kk] = pe[b*480 + j*15 + 7 + kk];
        }
        short8 px;
        #pragma unroll
        for (int kk = 0; kk < 8; ++kk) px[kk] = f2bf(v[kk]);
        *(short8*)&xb[j*136 + half*8] = px;
        short8 pad = {0,0,0,0,0,0,0,0};
        if (half == 0) pad[0] = (short)0x3F80;       // bf16(1.0) at col 16
        *(short8*)&xb[j*136 + 16 + half*8] = pad;
    }

    const short* wt1 = ws;
    const short* wt2 = ws + 4608;
    const short* wt3 = ws + 23040;

    // ================= layer 1 (K=16 padded to 32; bias folded) ====
    {
        gemm_ht<1,9,8>(xb, wt1, ss, c, q);
        f32x4 acc[8][2]; float rden[4][2];
        agg12(xb, ss, c, q, acc, rden);
        trans_phase<false>(acc, rden, nullptr, xb, c, q);
    }
    // ================= layer 2 (K=128) =============================
    {
        gemm_ht<4,9,8>(xb, wt2, ss, c, q);
        f32x4 acc[8][2]; float rden[4][2];
        agg12(xb, ss, c, q, acc, rden);
        trans_phase<true>(acc, rden, b2, xb, c, q);
    }
    // ================= layer 3 (packed 24+8, P-as-A agg, mean) =====
    {
        gemm3_ht(xb, wt3, ss, c, q, lane);
        agg3_mean(xb, ss, b3, ss, c, q);   // mcol aliases ss[0..23]
    }
    // ---- epilogue: out[g] = mcol @ lin_w + lin_b (f32) ----
    {
        float o = lb[lane];
        #pragma unroll
        for (int cc = 0; cc < 24; ++cc)
            o = fmaf(ss[cc], LW[cc*64 + lane], o);
        out[g*64 + lane] = o;
    }
}

extern "C" void kernel_launch(void* const* d_in, const int* in_sizes, int n_in,
                              void* d_out, int out_size, void* d_ws, size_t ws_size,
                              hipStream_t stream) {
    const float* xs  = (const float*)d_in[0];
    const float* pe  = (const float*)d_in[1];
    const float* W1  = (const float*)d_in[2];
    const float* as1 = (const float*)d_in[3];
    const float* ad1 = (const float*)d_in[4];
    const float* b1  = (const float*)d_in[5];
    const float* W2  = (const float*)d_in[6];
    const float* as2 = (const float*)d_in[7];
    const float* ad2 = (const float*)d_in[8];
    const float* b2  = (const float*)d_in[9];
    const float* W3  = (const float*)d_in[10];
    const float* as3 = (const float*)d_in[11];
    const float* ad3 = (const float*)d_in[12];
    const float* b3  = (const float*)d_in[13];
    const float* LW  = (const float*)d_in[14];
    const float* lb  = (const float*)d_in[15];
    float* o = (float*)d_out;
    short* ws = (short*)d_ws;

    int G = in_sizes[0] / 32;       // B*R graphs (16384)
    int B = in_sizes[1] / 480;      // pos_enc = B*32*15
    int R = G / B;

    build_wt<<<dim3(106), dim3(256), 0, stream>>>(W1, as1, ad1, b1, W2, as2, ad2,
                                                  W3, as3, ad3, ws);
    gat_mfma<<<dim3(G/4), dim3(256), 0, stream>>>(xs, pe, ws, b2, b3, LW, lb, o, R);
}

// Round 14
// 87.445 us; speedup vs baseline: 1.3980x; 1.0027x over previous
//
#include <hip/hip_runtime.h>
#include <hip/hip_bf16.h>

// GNN2: 3-layer GAT over 16384 independent 32-node cliques.
// One WAVE per graph (4 graphs / 256-thread block), zero barriers.
// mfma_f32_16x16x32_bf16 for GEMMs + aggregation; scores fused into the GEMM
// via pre-multiplied Wa = W @ [a_src|a_dst] columns pre-scaled by log2(e)
// (exp2-domain softmax, no max-subtraction). f32 accumulate.
// r13 + agg12 ILP restructure: per head-pair, issue all 8 ht ds_reads first,
// cover their ~120cy latency under the 4 pbuilds, then the 8-MFMA cluster.

typedef __attribute__((ext_vector_type(8))) short short8;
typedef __attribute__((ext_vector_type(4))) short short4v;
typedef __attribute__((ext_vector_type(4))) float f32x4;
typedef __attribute__((ext_vector_type(2))) float f32x2;

#define MFMA16(a,b,c) __builtin_amdgcn_mfma_f32_16x16x32_bf16(a,b,c,0,0,0)
#define L2E 1.4426950408889634f

__device__ __forceinline__ short f2bf(float f) {
    __hip_bfloat16 h = __float2bfloat16(f);
    return *reinterpret_cast<short*>(&h);
}
__device__ __forceinline__ float bf2f(short s) {
    unsigned int u = ((unsigned int)(unsigned short)s) << 16;
    return __builtin_bit_cast(float, u);
}
__device__ __forceinline__ float fexp2(float x) { return __builtin_amdgcn_exp2f(x); }
__device__ __forceinline__ float frcp(float x) {
    float r;
    asm volatile("v_rcp_f32 %0, %1" : "=v"(r) : "v"(x));
    return r;
}

// P-build for one (head, i-tile): e = lrelu(sd + sj) in log2 domain (packed f32x2
// adds/muls), p = exp2(e); returns unnormalized bf16 P-frag + 1/den.
__device__ __forceinline__ void pbuild(float sd, const f32x4 v0, const f32x4 v1,
                                       short8& t, float& rd)
{
    f32x2 sd2; sd2[0] = sd; sd2[1] = sd;
    f32x2 a0 = __builtin_shufflevector(v0, v0, 0, 1) + sd2;
    f32x2 a1 = __builtin_shufflevector(v0, v0, 2, 3) + sd2;
    f32x2 a2 = __builtin_shufflevector(v1, v1, 0, 1) + sd2;
    f32x2 a3 = __builtin_shufflevector(v1, v1, 2, 3) + sd2;
    a0 = __builtin_elementwise_max(a0, a0 * 0.2f);   // lrelu (log2 domain)
    a1 = __builtin_elementwise_max(a1, a1 * 0.2f);
    a2 = __builtin_elementwise_max(a2, a2 * 0.2f);
    a3 = __builtin_elementwise_max(a3, a3 * 0.2f);
    float p0 = fexp2(a0[0]), p1 = fexp2(a0[1]);
    float p2 = fexp2(a1[0]), p3 = fexp2(a1[1]);
    float p4 = fexp2(a2[0]), p5 = fexp2(a2[1]);
    float p6 = fexp2(a3[0]), p7 = fexp2(a3[1]);
    t[0] = f2bf(p0); t[1] = f2bf(p1); t[2] = f2bf(p2); t[3] = f2bf(p3);
    t[4] = f2bf(p4); t[5] = f2bf(p5); t[6] = f2bf(p6); t[7] = f2bf(p7);
    float den = ((p0 + p1) + (p2 + p3)) + ((p4 + p5) + (p6 + p7));
    den += __shfl_xor(den, 16, 64);
    den += __shfl_xor(den, 32, 64);
    rd = frcp(den);
}

// ---------------- pre-kernel: tiled transposed bf16 weights in ws ----------------
//  wt1 [0,4608):       NT=9, KC=1. n<128: k<16 -> W1[k][n], k==16 -> b1[n], else 0;
//                      n in 128..135 -> L2E*Wa1 (k<16 only); else 0
//  wt2 [4608,23040):   NT=9, KC=4. W2/Wa2
//  wt3 [23040,27136):  NT=2, KC=4. n<24 -> W3[k][n] (packed hd*6+dl); 24..31 -> L2E*Wa3
__global__ __launch_bounds__(256) void build_wt(
    const float* __restrict__ W1, const float* __restrict__ as1, const float* __restrict__ ad1,
    const float* __restrict__ B1,
    const float* __restrict__ W2, const float* __restrict__ as2, const float* __restrict__ ad2,
    const float* __restrict__ W3, const float* __restrict__ as3, const float* __restrict__ ad3,
    short* __restrict__ ws)
{
    int i = blockIdx.x * 256 + threadIdx.x;
    float val = 0.f;
    if (i < 4608) {                       // layer 1 (KC=1 -> [n][k])
        int n = i >> 5, k = i & 31;
        if (k < 16) {
            if (n < 128) val = W1[k*128 + n];
            else if (n < 136) {
                int cc = n - 128; const float* a = (cc < 4) ? as1 : ad1;
                for (int dl = 0; dl < 32; ++dl)
                    val += W1[k*128 + (cc&3)*32 + dl] * a[(cc&3)*32 + dl];
                val *= L2E;
            }
        } else if (k == 16 && n < 128) {
            val = B1[n];                  // bias row hit by constant-1 input col
        }
        ws[i] = f2bf(val);
    } else if (i < 23040) {               // layer 2
        int j = i - 4608;
        int kq = j & 31, c = (j >> 5) & 15, kc = (j >> 9) & 3, nt = j >> 11;
        int n = nt*16 + c, k = kc*32 + kq;
        if (n < 128) val = W2[k*128 + n];
        else if (n < 136) {
            int cc = n - 128; const float* a = (cc < 4) ? as2 : ad2;
            for (int dl = 0; dl < 32; ++dl)
                val += W2[k*128 + (cc&3)*32 + dl] * a[(cc&3)*32 + dl];
            val *= L2E;
        }
        ws[i] = f2bf(val);
    } else {                              // layer 3 (packed 24 + 8 score)
        int j = i - 23040;
        int kq = j & 31, c = (j >> 5) & 15, kc = (j >> 9) & 3, nt = j >> 11;
        int n = nt*16 + c, k = kc*32 + kq;
        if (n < 24) val = W3[k*24 + n];
        else {
            int cc = n - 24; const float* a = (cc < 4) ? as3 : ad3;
            for (int dl = 0; dl < 6; ++dl)
                val += W3[k*24 + (cc&3)*6 + dl] * a[(cc&3)*6 + dl];
            val *= L2E;
        }
        ws[i] = f2bf(val);
    }
}

// ---------------- main-kernel phases ----------------
// Fragment layout (gfx950 16x16x32 bf16): A: row=lane&15, k=8*(lane>>4)+v;
// B: col=lane&15, k=8*(lane>>4)+v; D: col=lane&15, row=4*(lane>>4)+r. [m89/m93]
// xb: [32][136] bf16. ht: [128][32] bf16 overlaid, 4-short granule gl of row d
// stored at gl ^ ((d&15)>>1). ss: f32[8][32] separate.

// GEMM + ht/score write, per-nt interleaved, B-frags double-buffered in regs.
template<int KC, int NT, int NTH>
__device__ __forceinline__ void gemm_ht(short* buf, const short* __restrict__ wt,
                                        float* ss, int c, int q)
{
    const f32x4 zf = {0.f, 0.f, 0.f, 0.f};
    short8 afr[2][KC];
    #pragma unroll
    for (int mt = 0; mt < 2; ++mt)
      #pragma unroll
      for (int kc = 0; kc < KC; ++kc)
        afr[mt][kc] = *(const short8*)&buf[(mt*16 + c)*136 + kc*32 + q*8];
    int sw = c >> 1;
    short8 bfr[2][KC];
    #pragma unroll
    for (int kc = 0; kc < KC; ++kc)
        bfr[0][kc] = *(const short8*)&wt[(kc*16 + c)*32 + q*8];
    #pragma unroll
    for (int nt = 0; nt < NT; ++nt) {
        const int cur = nt & 1, nxt = cur ^ 1;
        if (nt + 1 < NT) {
            #pragma unroll
            for (int kc = 0; kc < KC; ++kc)
                bfr[nxt][kc] = *(const short8*)&wt[(((nt+1)*KC + kc)*16 + c)*32 + q*8];
        }
        f32x4 a0 = zf, a1 = zf;
        __builtin_amdgcn_s_setprio(1);
        #pragma unroll
        for (int kc = 0; kc < KC; ++kc) {
            a0 = MFMA16(afr[0][kc], bfr[cur][kc], a0);
            a1 = MFMA16(afr[1][kc], bfr[cur][kc], a1);
        }
        __builtin_amdgcn_s_setprio(0);
        if (nt < NTH) {
            int d = nt*16 + c;
            short4v h0, h1;
            #pragma unroll
            for (int r = 0; r < 4; ++r) { h0[r] = f2bf(a0[r]); h1[r] = f2bf(a1[r]); }
            *(short4v*)&buf[d*32 + ((q ^ sw))*4]     = h0;
            *(short4v*)&buf[d*32 + (((4+q) ^ sw))*4] = h1;
        } else if (c < 8) {   // score tile: rows c<4 = s_src head c, c>=4 = s_dst
            *(f32x4*)&ss[c*32 + q*4]      = a0;
            *(f32x4*)&ss[c*32 + 16 + q*4] = a1;
        }
    }
}

// Fused frag+agg (layers 1-2), head-pair halves: issue all 8 ht reads of the
// pair first, cover DS latency under the 4 pbuilds, then 8-MFMA cluster.
__device__ __forceinline__ void agg12(const short* buf, const float* ss,
                                      int c, int q, f32x4 (&acc)[8][2], float (&rden)[4][2])
{
    const f32x4 zf = {0.f, 0.f, 0.f, 0.f};
    int sw = c >> 1;
    #pragma unroll
    for (int hp = 0; hp < 2; ++hp) {        // head pair: hd = 2hp, 2hp+1
        short8 af[4];
        #pragma unroll
        for (int k = 0; k < 4; ++k) {       // mt = hp*4 + k
            int d = (hp*4 + k)*16 + c;
            short4v lo = *(const short4v*)&buf[d*32 + ((2*q)   ^ sw)*4];
            short4v hi = *(const short4v*)&buf[d*32 + ((2*q+1) ^ sw)*4];
            af[k] = __builtin_shufflevector(lo, hi, 0,1,2,3,4,5,6,7);
        }
        short8 pf[2][2];
        #pragma unroll
        for (int hh = 0; hh < 2; ++hh) {
            int hd = hp*2 + hh;
            f32x4 v0 = *(const f32x4*)&ss[hd*32 + q*8];
            f32x4 v1 = *(const f32x4*)&ss[hd*32 + q*8 + 4];
            #pragma unroll
            for (int it = 0; it < 2; ++it) {
                float sd = ss[(4+hd)*32 + it*16 + c];
                pbuild(sd, v0, v1, pf[hh][it], rden[hd][it]);
            }
        }
        __builtin_amdgcn_s_setprio(1);
        #pragma unroll
        for (int k = 0; k < 4; ++k) {
            int mt = hp*4 + k, hh = k >> 1;
            acc[mt][0] = MFMA16(af[k], pf[hh][0], zf);
            acc[mt][1] = MFMA16(af[k], pf[hh][1], zf);
        }
        __builtin_amdgcn_s_setprio(0);
    }
}

// Layer transition: xb[i][d] = agg*rden (+ bias), packed b64 writes.
template<bool BIAS>
__device__ __forceinline__ void trans_phase(const f32x4 (&acc)[8][2], const float (&rden)[4][2],
                                            const float* bias, short* xb, int c, int q)
{
    #pragma unroll
    for (int mt = 0; mt < 8; ++mt) {
        f32x4 bv;
        if (BIAS) bv = *(const f32x4*)&bias[mt*16 + q*4];
        #pragma unroll
        for (int nt = 0; nt < 2; ++nt) {
            float rd = rden[mt >> 1][nt];
            int ii = nt*16 + c;
            short4v o;
            #pragma unroll
            for (int r = 0; r < 4; ++r)
                o[r] = f2bf(BIAS ? fmaf(acc[mt][nt][r], rd, bv[r]) : acc[mt][nt][r] * rd);
            *(short4v*)&xb[ii*136 + mt*16 + q*4] = o;
        }
    }
}

// Layer-3 GEMM: packed cols [24 h | 8 score], NT=2; ht rows head-padded hd*16+dl,
// pad rows zero-filled (after A-frag preload frees the xb region).
__device__ __forceinline__ void gemm3_ht(short* buf, const short* __restrict__ wt,
                                         float* ss, int c, int q, int lane)
{
    const f32x4 zf = {0.f, 0.f, 0.f, 0.f};
    short8 afr[2][4];
    #pragma unroll
    for (int mt = 0; mt < 2; ++mt)
      #pragma unroll
      for (int kc = 0; kc < 4; ++kc)
        afr[mt][kc] = *(const short8*)&buf[(mt*16 + c)*136 + kc*32 + q*8];
    short8 bfr[2][4];
    #pragma unroll
    for (int kc = 0; kc < 4; ++kc)
        bfr[0][kc] = *(const short8*)&wt[(kc*16 + c)*32 + q*8];
    {   // zero-fill pad rows hd*16+dl, dl in 6..15 (40 rows x 8 granules)
        const short4v z4 = {0, 0, 0, 0};
        #pragma unroll
        for (int k = 0; k < 5; ++k) {
            int flat = lane + k*64;
            int z = flat >> 3, gg = flat & 7;
            int row = (z/10)*16 + 6 + (z%10);
            *(short4v*)&buf[row*32 + gg*4] = z4;
        }
    }
    #pragma unroll
    for (int nt = 0; nt < 2; ++nt) {
        const int cur = nt & 1, nxt = cur ^ 1;
        if (nt + 1 < 2) {
            #pragma unroll
            for (int kc = 0; kc < 4; ++kc)
                bfr[nxt][kc] = *(const short8*)&wt[(((nt+1)*4 + kc)*16 + c)*32 + q*8];
        }
        f32x4 a0 = zf, a1 = zf;
        __builtin_amdgcn_s_setprio(1);
        #pragma unroll
        for (int kc = 0; kc < 4; ++kc) {
            a0 = MFMA16(afr[0][kc], bfr[cur][kc], a0);
            a1 = MFMA16(afr[1][kc], bfr[cur][kc], a1);
        }
        __builtin_amdgcn_s_setprio(0);
        int p = nt*16 + c;
        if (p < 24) {
            int row = (p/6)*16 + (p%6);
            int sw3 = (row & 15) >> 1;
            short4v h0, h1;
            #pragma unroll
            for (int r = 0; r < 4; ++r) { h0[r] = f2bf(a0[r]); h1[r] = f2bf(a1[r]); }
            *(short4v*)&buf[row*32 + ((q ^ sw3))*4]     = h0;
            *(short4v*)&buf[row*32 + (((4+q) ^ sw3))*4] = h1;
        } else if (c >= 8) {   // score cols
            *(f32x4*)&ss[(c-8)*32 + q*4]      = a0;
            *(f32x4*)&ss[(c-8)*32 + 16 + q*4] = a1;
        }
    }
}

// Layer-3 aggregation with P as A-operand + in-register node-mean -> mcol[24].
__device__ __forceinline__ void agg3_mean(const short* buf, const float* ss,
                                          const float* b3, float* mcol, int c, int q)
{
    const f32x4 zf = {0.f, 0.f, 0.f, 0.f};
    int sw = c >> 1;
    float vout[4];
    #pragma unroll
    for (int hd = 0; hd < 4; ++hd) {
        f32x4 v0 = *(const f32x4*)&ss[hd*32 + q*8];
        f32x4 v1 = *(const f32x4*)&ss[hd*32 + q*8 + 4];
        int rl = hd*16 + c;
        short4v lo = *(const short4v*)&buf[rl*32 + ((2*q)   ^ sw)*4];
        short4v hi = *(const short4v*)&buf[rl*32 + ((2*q+1) ^ sw)*4];
        short8 bf_ = __builtin_shufflevector(lo, hi, 0,1,2,3,4,5,6,7);
        short8 pf[2];
        #pragma unroll
        for (int it = 0; it < 2; ++it) {
            float sd = ss[(4+hd)*32 + it*16 + c];
            float rd;
            short8 t;
            pbuild(sd, v0, v1, t, rd);
            #pragma unroll
            for (int v = 0; v < 8; ++v)
                t[v] = f2bf(bf2f(t[v]) * rd);
            pf[it] = t;
        }
        __builtin_amdgcn_s_setprio(1);
        f32x4 o0 = MFMA16(pf[0], bf_, zf);   // D: row=i(4q+r), col=dl(c) in head hd
        f32x4 o1 = MFMA16(pf[1], bf_, zf);
        __builtin_amdgcn_s_setprio(0);
        float s = (o0[0]+o0[1]) + (o0[2]+o0[3]) + (o1[0]+o1[1]) + (o1[2]+o1[3]);
        s += __shfl_xor(s, 16, 64);
        s += __shfl_xor(s, 32, 64);
        vout[hd] = s;
    }
    if (q == 0 && c < 6) {
        #pragma unroll
        for (int hd = 0; hd < 4; ++hd)
            mcol[hd*6 + c] = vout[hd] * (1.f/32.f) + b3[hd*6 + c];
    }
}

__global__ __launch_bounds__(256, 4) void gat_mfma(
    const float* __restrict__ xs, const float* __restrict__ pe,
    const short* __restrict__ ws,
    const float* __restrict__ b2, const float* __restrict__ b3,
    const float* __restrict__ LW, const float* __restrict__ lb,
    float* __restrict__ out, int R)
{
    __shared__ short buf[4][4352];      // per-wave union: xb[32][136] <-> ht[*][32] (swz)
    __shared__ float ssx[4][256];       // [8][32] scores; mcol aliases [0..23]

    int t = threadIdx.x;
    int w = t >> 6, lane = t & 63;
    int c = lane & 15, q = lane >> 4;
    int g = blockIdx.x * 4 + w;
    int b = g / R;

    short* xb = buf[w];
    float* ss = ssx[w];

    // ---- build x0 [32][16] bf16; col 16 = 1.0 (bias row), 17..31 = 0 ----
    {
        int j = lane >> 1, half = lane & 1;
        float v[8];
        if (half == 0) {
            v[0] = xs[g*32 + j];
            #pragma unroll
            for (int kk = 0; kk < 7; ++kk) v[1+kk] = pe[b*480 + j*15 + kk];
        } else {
            #pragma unroll
            for (int kk = 0; kk < 8; ++kk) v[kk] = pe[b*480 + j*15 + 7 + kk];
        }
        short8 px;
        #pragma unroll
        for (int kk = 0; kk < 8; ++kk) px[kk] = f2bf(v[kk]);
        *(short8*)&xb[j*136 + half*8] = px;
        short8 pad = {0,0,0,0,0,0,0,0};
        if (half == 0) pad[0] = (short)0x3F80;       // bf16(1.0) at col 16
        *(short8*)&xb[j*136 + 16 + half*8] = pad;
    }

    const short* wt1 = ws;
    const short* wt2 = ws + 4608;
    const short* wt3 = ws + 23040;

    // ================= layer 1 (K=16 padded to 32; bias folded) ====
    {
        gemm_ht<1,9,8>(xb, wt1, ss, c, q);
        f32x4 acc[8][2]; float rden[4][2];
        agg12(xb, ss, c, q, acc, rden);
        trans_phase<false>(acc, rden, nullptr, xb, c, q);
    }
    // ================= layer 2 (K=128) =============================
    {
        gemm_ht<4,9,8>(xb, wt2, ss, c, q);
        f32x4 acc[8][2]; float rden[4][2];
        agg12(xb, ss, c, q, acc, rden);
        trans_phase<true>(acc, rden, b2, xb, c, q);
    }
    // ================= layer 3 (packed 24+8, P-as-A agg, mean) =====
    {
        gemm3_ht(xb, wt3, ss, c, q, lane);
        agg3_mean(xb, ss, b3, ss, c, q);   // mcol aliases ss[0..23]
    }
    // ---- epilogue: out[g] = mcol @ lin_w + lin_b (f32) ----
    {
        float o = lb[lane];
        #pragma unroll
        for (int cc = 0; cc < 24; ++cc)
            o = fmaf(ss[cc], LW[cc*64 + lane], o);
        out[g*64 + lane] = o;
    }
}

extern "C" void kernel_launch(void* const* d_in, const int* in_sizes, int n_in,
                              void* d_out, int out_size, void* d_ws, size_t ws_size,
                              hipStream_t stream) {
    const float* xs  = (const float*)d_in[0];
    const float* pe  = (const float*)d_in[1];
    const float* W1  = (const float*)d_in[2];
    const float* as1 = (const float*)d_in[3];
    const float* ad1 = (const float*)d_in[4];
    const float* b1  = (const float*)d_in[5];
    const float* W2  = (const float*)d_in[6];
    const float* as2 = (const float*)d_in[7];
    const float* ad2 = (const float*)d_in[8];
    const float* b2  = (const float*)d_in[9];
    const float* W3  = (const float*)d_in[10];
    const float* as3 = (const float*)d_in[11];
    const float* ad3 = (const float*)d_in[12];
    const float* b3  = (const float*)d_in[13];
    const float* LW  = (const float*)d_in[14];
    const float* lb  = (const float*)d_in[15];
    float* o = (float*)d_out;
    short* ws = (short*)d_ws;

    int G = in_sizes[0] / 32;       // B*R graphs (16384)
    int B = in_sizes[1] / 480;      // pos_enc = B*32*15
    int R = G / B;

    build_wt<<<dim3(106), dim3(256), 0, stream>>>(W1, as1, ad1, b1, W2, as2, ad2,
                                                  W3, as3, ad3, ws);
    gat_mfma<<<dim3(G/4), dim3(256), 0, stream>>>(xs, pe, ws, b2, b3, LW, lb, o, R);
}